// Round 13
// baseline (133.453 us; speedup 1.0000x reference)
//
#include <hip/hip_runtime.h>

#define IMG_H 768
#define IMG_W 768
#define N_IMG 32
#define INV_LOG2 1.44269504088896340736f
#define STRIPS 13            // ceil(768 / 60) output strips of 60 cols
#define ROWS_PER_WAVE 48     // 768 = 4 bands x 4 waves x 48 rows

__device__ __forceinline__ float bperm(int addr, float v) {
    return __int_as_float(__builtin_amdgcn_ds_bpermute(addr, __float_as_int(v)));
}

// Lane-per-column stencil: wave = 64 columns (2+60+2), marches 48 rows.
// No LDS tiles, no barriers. Vertical 5-row window in registers (ring + V1/V2
// incremental); horizontal 5-window via ds_bpermute. y/gt prefetched 1 row.
__global__ __launch_bounds__(256) void wk_pass1(
    const float* __restrict__ y_d, const float* __restrict__ y_gt,
    float* __restrict__ out, float* __restrict__ sums)
{
    const int b = blockIdx.x;
    const int img = b / (STRIPS * 4);
    const int rem = b - img * (STRIPS * 4);
    const int strip = rem >> 2;        // 0..12
    const int band = rem & 3;          // 0..3

    const int tid  = threadIdx.x;
    const int wid  = tid >> 6;
    const int lane = tid & 63;
    const int r0   = band * 192 + wid * ROWS_PER_WAVE;
    const int col  = strip * 60 - 2 + lane;
    const bool colv   = (unsigned)col < (unsigned)IMG_W;
    const bool out_ok = (lane >= 2) && (lane <= 61) && colv;

    const size_t img_off = (size_t)img * IMG_H * IMG_W;
    const float* __restrict__ yimg = y_d + img_off;
    const float* __restrict__ gimg = y_gt + img_off;
    float* __restrict__ oimg = out + img_off;

    // per-lane constants (garbage for !colv lanes; never consumed)
    const int   cx  = min(col, 2) + min(IMG_W - 1 - col, 2) + 1;
    const float C5  = 5.0f * (float)cx;
    const float rc5 = __fdividef(1.0f, C5 - 1.0f);

    const int a_up1 = (lane >= 1 ? lane - 1 : 0) << 2;
    const int a_up2 = (lane >= 2 ? lane - 2 : 0) << 2;
    const int a_dn2 = (lane <= 61 ? lane + 2 : 63) << 2;

    int off = r0 * IMG_W + col;        // offset of row r0, own column

    // ---- prime: p-ring rows r0-3..r0+1 (OOB -> p = 0: the analytic C-1
    // normalization relies on OOB window entries contributing zero) ----
    float p0, p1, p2, p3, p4, eA, eB;
    {
        float pk[5], yk[5];
#pragma unroll
        for (int k = 0; k < 5; ++k) {
            int row = r0 - 3 + k;
            bool ok = colv && (row >= 0);
            yk[k] = ok ? yimg[off + (k - 3) * IMG_W] : 0.0f;
            float E  = __expf(-fabsf(yk[k]));
            float t2 = 1.0f + E;
            float rr = __fdividef(1.0f, t2);
            float pr = (yk[k] >= 0.0f) ? rr : E * rr;
            pk[k] = ok ? pr : 0.0f;
        }
        // ent for rows r0, r0+1 (always in-bounds rows)
        float e_[2];
#pragma unroll
        for (int k = 3; k <= 4; ++k) {
            float yv = yk[k];
            float E  = __expf(-fabsf(yv));
            float t2 = 1.0f + E;
            float rr = __fdividef(1.0f, t2);
            float pr = (yv >= 0.0f) ? rr : E * rr;
            float sp = fmaxf(yv, 0.0f) + __logf(t2);
            e_[k - 3] = fmaf(fmaf(pr, yv, -sp), INV_LOG2, 1.0f);
        }
        eA = e_[0]; eB = e_[1];
        p0 = pk[0]; p1 = pk[1]; p2 = pk[2]; p3 = pk[3]; p4 = pk[4];
    }
    float V1 = ((p0 + p1) + (p2 + p3)) + p4;
    float V2 = ((p0*p0 + p1*p1) + (p2*p2 + p3*p3)) + p4*p4;

    float ynext = colv ? yimg[off + 2 * IMG_W] : 0.0f;   // row r0+2 (<=722, valid)
    float gtcur = colv ? gimg[off] : 0.0f;               // row r0
    float lsum = 0.0f;

#pragma unroll 4
    for (int r = r0; r < r0 + ROWS_PER_WAVE; ++r) {
        // 1. prefetch next-row streams (consumed next iteration)
        float yfar = (colv && (r + 3 < IMG_H)) ? yimg[off + 3 * IMG_W] : 0.0f;
        float gtn  = (colv && (r + 1 < IMG_H)) ? gimg[off + IMG_W] : 0.0f;

        // 2. p/ent for incoming row r+2 (from ynext, loaded last iter)
        float yv = ynext;
        float E  = __expf(-fabsf(yv));
        float t2 = 1.0f + E;
        float rr = __fdividef(1.0f, t2);
        float praw = (yv >= 0.0f) ? rr : E * rr;
        float sp = fmaxf(yv, 0.0f) + __logf(t2);
        float ei = fmaf(fmaf(praw, yv, -sp), INV_LOG2, 1.0f);
        float pi = (colv && (r + 2 < IMG_H)) ? praw : 0.0f;

        // 3. vertical window update: rows r-2..r+2
        V1 += pi - p0;
        V2 += fmaf(pi, pi, -(p0 * p0));

        // 4. horizontal 5-window sums via bpermute:
        //    S[c] = V[c-2] + (V[c]+V[c-1]) + (V[c+2]+V[c+1])
        float A1 = V1 + bperm(a_up1, V1);
        float S1 = bperm(a_up2, V1) + A1 + bperm(a_dn2, A1);
        float A2 = V2 + bperm(a_up1, V2);
        float S2 = bperm(a_up2, V2) + A2 + bperm(a_dn2, A2);

        // 5. weight for output row r (center p = ring slot p3, ent = eA)
        float pc = p3;
        float acc, rcv;
        if (r >= 2 && r <= IMG_H - 3) {          // wave-uniform branch
            acc = fmaf(C5 * pc, pc, fmaf(-2.0f * pc, S1, S2));
            rcv = rc5;
        } else {
            float cy = (float)(min(r, 2) + min(IMG_H - 1 - r, 2) + 1);
            float C  = cy * (float)cx;
            acc = fmaf(C * pc, pc, fmaf(-2.0f * pc, S1, S2));
            rcv = __fdividef(1.0f, C - 1.0f);
        }
        float cons = fmaf(-acc, rcv, 1.0f);
        float w = fmaxf(cons * eA, gtcur);
        w = fmaf(w, 0.9f, 0.1f);
        if (out_ok) oimg[off] = w;
        lsum += out_ok ? w : 0.0f;

        // 6. shift rings / advance
        p0 = p1; p1 = p2; p2 = p3; p3 = p4; p4 = pi;
        eA = eB; eB = ei;
        ynext = yfar; gtcur = gtn;
        off += IMG_W;
    }

    // ---- per-image sum: wave shfl-reduce -> one atomic per wave ----
#pragma unroll
    for (int o = 32; o > 0; o >>= 1)
        lsum += __shfl_down(lsum, o, 64);
    if (lane == 0)
        atomicAdd(&sums[img], lsum);
}

// Pass 2: divide by per-image mean.
__global__ __launch_bounds__(256) void wk_pass2(
    float* __restrict__ out, const float* __restrict__ sums)
{
    const size_t total4 = (size_t)N_IMG * IMG_H * IMG_W / 4;
    const int per_img4 = IMG_H * IMG_W / 4;   // 147456
    for (size_t i = (size_t)blockIdx.x * blockDim.x + threadIdx.x; i < total4;
         i += (size_t)gridDim.x * blockDim.x) {
        int img = (int)(i / per_img4);
        float scale = (float)(IMG_H * IMG_W) / sums[img];
        float4 v = reinterpret_cast<float4*>(out)[i];
        v.x *= scale; v.y *= scale; v.z *= scale; v.w *= scale;
        reinterpret_cast<float4*>(out)[i] = v;
    }
}

extern "C" void kernel_launch(void* const* d_in, const int* in_sizes, int n_in,
                              void* d_out, int out_size, void* d_ws, size_t ws_size,
                              hipStream_t stream) {
    const float* y_d  = (const float*)d_in[0];
    const float* y_gt = (const float*)d_in[1];
    float* out  = (float*)d_out;
    float* sums = (float*)d_ws;

    hipMemsetAsync(sums, 0, N_IMG * sizeof(float), stream);

    wk_pass1<<<dim3(N_IMG * STRIPS * 4), dim3(256), 0, stream>>>(y_d, y_gt, out, sums);
    wk_pass2<<<dim3(2048), dim3(256), 0, stream>>>(out, sums);
}